// Round 11
// baseline (706.257 us; speedup 1.0000x reference)
//
#include <hip/hip_runtime.h>
#include <stdint.h>

typedef uint16_t u16;
typedef uint32_t u32;

#define N_NODESC 100000
#define N_EDGESC 400000
#define E_TOT    500000   // edges + self loops
#define HID      256
#define NLAYERS  4
#define NGRAPHS  128
#define SEQLEN   5
#define VOCABC   5002
#define MAXDEPTH 20
#define NEG_SLOPE 0.2f
#define BN_EPSC  1e-5f
#define LOG2E    1.4426950408889634f
#define NCHUNK   ((N_NODESC + 255)/256)   // 391
#define NCH64    ((N_NODESC + 63)/64)     // 1563 (64-row chunks)
#define NROWT    (N_NODESC/16)            // 6250 row tiles, exact
#define NPAIR    (N_NODESC/2)             // 50000 node pairs for paired attention
#define NPART    64                       // BN partial rows (each 512 floats: 256 sum + 256 sq)
#define NVQ      ((VOCABC + 63)/64)       // 79 vocab quads for k_pred
#define ATTNB    2048                     // grid for k_attn_gout
#define GEMMB    512                      // grid for k_gemm (~12 tiles/block, 2-deep pipeline)
#define LDSROW   264                      // padded LDS row (u16): 2-way alias only

typedef __attribute__((ext_vector_type(8))) short short8;
typedef __attribute__((ext_vector_type(4))) float f32x4;
typedef __attribute__((ext_vector_type(4))) unsigned short u16x4;
typedef __attribute__((ext_vector_type(8))) unsigned short u16x8;

__device__ __forceinline__ float b2f(u16 u){
  union { u32 i; float f; } v; v.i = ((u32)u) << 16; return v.f;
}
__device__ __forceinline__ u16 f2b(float f){
  union { float f; u32 i; } v; v.f = f;
  u32 u = v.i;
  u += 0x7FFFu + ((u >> 16) & 1u);   // RNE
  return (u16)(u >> 16);
}
// raw v_exp_f32 (exp2). s_nop covers the trans-op -> dependent-VALU wait state.
__device__ __forceinline__ float fexp2(float x){
  float r;
  asm("v_exp_f32 %0, %1\n\ts_nop 0" : "=v"(r) : "v"(x));
  return r;
}
// dual-dtype parameter load: flag=1 -> f32, flag=0 -> bf16
__device__ __forceinline__ float ldp(const void* p, size_t i, int f){
  return f ? ((const float*)p)[i] : b2f(((const u16*)p)[i]);
}
// 4-wide dual-dtype load (i must be 4-element aligned)
__device__ __forceinline__ f32x4 ld4(const void* p, size_t i, int f){
  f32x4 r;
  if (f){
    r = *(const f32x4*)((const float*)p + i);
  } else {
    const u16x4 u = *(const u16x4*)((const u16*)p + i);
    r[0] = b2f(u[0]); r[1] = b2f(u[1]); r[2] = b2f(u[2]); r[3] = b2f(u[3]);
  }
  return r;
}

// ---------------- dtype detector: sample type_emb both ways ----------------
__global__ __launch_bounds__(64) void k_detect(const void* temb, int* flag){
  int lane = threadIdx.x;
  const u32* w32 = (const u32*)temb;
  int sf = 0, sb = 0;
  for (int i = lane; i < 256; i += 64){
    u32 w = w32[i];
    union { u32 u; float f; } cf; cf.u = w;
    float af = fabsf(cf.f);
    if (cf.f == 0.0f || (af >= 1e-12f && af <= 4096.f)) sf++;
    float b0 = b2f((u16)(w & 0xFFFFu));
    float b1 = b2f((u16)(w >> 16));
    float a0 = fabsf(b0), a1 = fabsf(b1);
    if (b0 == 0.f || (a0 >= 1e-12f && a0 <= 4096.f)) sb++;
    if (b1 == 0.f || (a1 >= 1e-12f && a1 <= 4096.f)) sb++;
  }
  #pragma unroll
  for (int o = 1; o < 64; o <<= 1){ sf += __shfl_xor(sf, o); sb += __shfl_xor(sb, o); }
  if (lane == 0) *flag = (2*sf > sb) ? 1 : 0;
}

// ---------------- utility ----------------
__global__ __launch_bounds__(256) void k_zero(int* __restrict__ p, int n){
  int i = blockIdx.x*256 + threadIdx.x;
  if (i < n) p[i] = 0;
}

// ---------------- embedding: 64-node chunks, lane owns 4 channels; zeroes cursor ----------------
__global__ __launch_bounds__(256) void k_embed(const int* __restrict__ x, const int* __restrict__ nd,
    const void* __restrict__ temb, const void* __restrict__ aemb, const void* __restrict__ demb,
    u16* __restrict__ h, const int* __restrict__ flagp, int* __restrict__ cursor){
  int f = *flagp;
  int tid = threadIdx.x;
  int r0 = blockIdx.x*64;
  if (tid < 64 && r0 + tid < N_NODESC) cursor[r0 + tid] = 0;
  int wid = tid >> 6, lane = tid & 63;
  int c4 = lane*4;
  #pragma unroll 4
  for (int k = 0; k < 16; ++k){
    int n = r0 + wid*16 + k;
    if (n >= N_NODESC) break;
    int t = x[n*2+0], a = x[n*2+1];
    if (t < 0) t = 0; if (t > 97) t = 97;
    if (a < 0) a = 0; if (a > 10029) a = 10029;
    int d = nd[n]; if (d > MAXDEPTH) d = MAXDEPTH; if (d < 0) d = 0;
    const f32x4 vt = ld4(temb, (size_t)t*HID + c4, f);
    const f32x4 va = ld4(aemb, (size_t)a*HID + c4, f);
    const f32x4 vd = ld4(demb, (size_t)d*HID + c4, f);
    u16x4 o;
    #pragma unroll
    for (int j = 0; j < 4; ++j) o[j] = f2b(vt[j] + va[j] + vd[j]);
    *(u16x4*)(h + (size_t)n*HID + c4) = o;
  }
}

// ---------------- edge sort by dst (counting sort) ----------------
__global__ __launch_bounds__(256) void k_hist(const int* __restrict__ ei, int* __restrict__ cnt){
  int e = blockIdx.x*256 + threadIdx.x;
  if (e >= E_TOT) return;
  int dst = (e < N_EDGESC) ? ei[N_EDGESC + e] : (e - N_EDGESC);
  if ((unsigned)dst >= N_NODESC) return;
  atomicAdd(&cnt[dst], 1);
}

// hierarchical scan, phase 1: per-256-chunk exclusive scan + chunk total
__global__ __launch_bounds__(256) void k_scan_part(const int* __restrict__ cnt,
    int* __restrict__ off, int* __restrict__ btot){
  __shared__ int lds[256];
  int b = blockIdx.x, tid = threadIdx.x;
  int i = b*256 + tid;
  int v = (i < N_NODESC) ? cnt[i] : 0;
  lds[tid] = v;
  __syncthreads();
  #pragma unroll
  for (int s = 1; s < 256; s <<= 1){
    int t = (tid >= s) ? lds[tid - s] : 0;
    __syncthreads();
    lds[tid] += t;
    __syncthreads();
  }
  if (i < N_NODESC) off[i] = lds[tid] - v;   // chunk-local exclusive
  if (tid == 255) btot[b] = lds[255];
}

// phase 2: scan the 391 chunk totals (1 block), write grand total to offN
__global__ __launch_bounds__(256) void k_scan_tot(const int* __restrict__ btot,
    int* __restrict__ boff, int* __restrict__ offN){
  __shared__ int lds[256];
  __shared__ int s_carry;
  int tid = threadIdx.x;
  if (tid == 0) s_carry = 0;
  __syncthreads();
  for (int base = 0; base < NCHUNK; base += 256){
    int i = base + tid;
    int v = (i < NCHUNK) ? btot[i] : 0;
    lds[tid] = v;
    __syncthreads();
    #pragma unroll
    for (int s = 1; s < 256; s <<= 1){
      int t = (tid >= s) ? lds[tid - s] : 0;
      __syncthreads();
      lds[tid] += t;
      __syncthreads();
    }
    if (i < NCHUNK) boff[i] = s_carry + lds[tid] - v;
    __syncthreads();
    if (tid == 255) s_carry += lds[255];
    __syncthreads();
  }
  if (tid == 0) *offN = s_carry;
}

// phase 3: add chunk offsets; also re-zero cursor for the scatter pass
__global__ __launch_bounds__(256) void k_scan_add(int* __restrict__ off,
    const int* __restrict__ boff, int* __restrict__ cursor){
  int b = blockIdx.x;
  int i = b*256 + threadIdx.x;
  if (i < N_NODESC){ off[i] += boff[b]; cursor[i] = 0; }
}

__global__ __launch_bounds__(256) void k_scatter(const int* __restrict__ ei,
    const int* __restrict__ soff, int* __restrict__ cursor, int* __restrict__ ssorted){
  int e = blockIdx.x*256 + threadIdx.x;
  if (e >= E_TOT) return;
  int src = (e < N_EDGESC) ? ei[e]            : (e - N_EDGESC);
  int dst = (e < N_EDGESC) ? ei[N_EDGESC + e] : (e - N_EDGESC);
  if ((unsigned)dst >= N_NODESC || (unsigned)src >= N_NODESC) return;
  int pos = soff[dst] + atomicAdd(&cursor[dst], 1);
  if ((unsigned)pos < E_TOT) ssorted[pos] = src;
}

// ---------------- fused prep: W transpose (blocks 0..1023) + VA precompute (blocks 1024..1027) ----------------
// VA inner loop vectorized 4-wide (was 256 scalar-load iterations -> 64).
__global__ __launch_bounds__(256) void k_prep(const void* __restrict__ W, u16* __restrict__ WT,
    const void* __restrict__ asrc, const void* __restrict__ adst,
    u16* __restrict__ VAT, const int* __restrict__ flagp){
  int f = *flagp;
  int bx = blockIdx.x;
  if (bx < 256*NLAYERS){
    int l = bx >> 8, n2 = bx & 255, k = threadIdx.x;
    WT[(l*HID + n2)*HID + k] = f2b(ldp(W, (size_t)(l*HID + k)*HID + n2, f));
    return;
  }
  int l = bx - 256*NLAYERS;          // 0..NLAYERS-1
  int i = threadIdx.x;               // input channel
  int H = (l == NLAYERS-1) ? 1 : 8;
  float col[16];
  #pragma unroll
  for (int c = 0; c < 16; ++c) col[c] = 0.f;
  const size_t wrow = ((size_t)l*HID + i)*HID;
  const size_t arow = (size_t)l*HID;
  if (H == 8){
    for (int h = 0; h < 8; ++h){
      float vs = 0.f, vd = 0.f;
      for (int o = h*32; o < h*32+32; o += 4){
        f32x4 w = ld4(W, wrow + o, f);
        f32x4 as = ld4(asrc, arow + o, f);
        f32x4 ad = ld4(adst, arow + o, f);
        #pragma unroll
        for (int j = 0; j < 4; ++j){ vs += w[j]*as[j]; vd += w[j]*ad[j]; }
      }
      col[h*2] = vs; col[h*2+1] = vd;
    }
  } else {
    float vs = 0.f, vd = 0.f;
    for (int o = 0; o < HID; o += 4){
      f32x4 w = ld4(W, wrow + o, f);
      f32x4 as = ld4(asrc, arow + o, f);
      f32x4 ad = ld4(adst, arow + o, f);
      #pragma unroll
      for (int j = 0; j < 4; ++j){ vs += w[j]*as[j]; vd += w[j]*ad[j]; }
    }
    col[0] = vs; col[1] = vd;
  }
  #pragma unroll
  for (int c = 0; c < 16; ++c)
    VAT[((size_t)l*16 + c)*HID + i] = f2b(col[c]);
}

// ---------------- GEMM + fused prev-layer BN apply + fused scores (17th B-tile) ----------------
// 8-wave (512-thread) blocks, 2 B-tiles/wave; swapped MFMA operand order (D col=node).
// One raw s_barrier per tile; lgkmcnt-only drain. 2-tile-deep rotating register
// prefetch; grid 512 so each block runs ~12 tiles (pipeline amortized).
__global__ __launch_bounds__(512) void k_gemm(u16* __restrict__ h,
    const u16* __restrict__ gout, const float* __restrict__ scale,
    const float* __restrict__ shift, int doApply,
    const u16* __restrict__ WT, const u16* __restrict__ VAT,
    u16* __restrict__ hh, float* __restrict__ ssrc, float* __restrict__ sdst,
    int H, float* __restrict__ bnpart){
  __shared__ u16 hA[2][16*LDSROW];
  int tid = threadIdx.x;
  if (blockIdx.x < NPART) bnpart[blockIdx.x*512 + tid] = 0.f;
  int wave = tid >> 6, lane = tid & 63;
  int m = lane & 15, quad = lane >> 4;
  int prow = tid >> 5, pch = (tid & 31)*8;   // staging: thread owns (row=prow, ch pch..pch+7)

  // 2 B-tiles per wave (col-tiles wave*2, wave*2+1)
  short8 B[2][8];
  #pragma unroll
  for (int jj = 0; jj < 2; ++jj){
    const u16* wp = WT + (size_t)(((wave*2 + jj)*16 + m)*HID) + quad*8;
    #pragma unroll
    for (int ks = 0; ks < 8; ++ks)
      B[jj][ks] = *(const short8*)(wp + ks*32);
  }
  short8 B5[8];
  if (wave == 0){
    const u16* vp = VAT + (size_t)m*HID + quad*8;
    #pragma unroll
    for (int ks = 0; ks < 8; ++ks)
      B5[ks] = *(const short8*)(vp + ks*32);
  }

  // hoisted BN scale/shift for this thread's 8 channels
  f32x4 sc0 = {}, sc1 = {}, sh0 = {}, sh1 = {};
  if (doApply){
    sc0 = *(const f32x4*)(scale + pch);     sh0 = *(const f32x4*)(shift + pch);
    sc1 = *(const f32x4*)(scale + pch + 4); sh1 = *(const f32x4*)(shift + pch + 4);
  }

  const int G = gridDim.x;
  int t = blockIdx.x;
  if (t >= NROWT) return;     // uniform per block

  // prologue: 2 tiles in flight (sets a=tile t, b=tile t+G)
  short8 ha, ga = {}, hb, gb = {};
  {
    size_t base = (size_t)(t*16 + prow)*HID + pch;
    ha = *(const short8*)(h + base);
    if (doApply) ga = *(const short8*)(gout + base);
  }
  {
    int t1 = t + G;
    if (t1 < NROWT){
      size_t base = (size_t)(t1*16 + prow)*HID + pch;
      hb = *(const short8*)(h + base);
      if (doApply) gb = *(const short8*)(gout + base);
    } else { hb = ha; gb = ga; }
  }

  int p = 0;
  for (;;){
    // ---- stage: BN apply (prev layer) + h writeback + LDS write (set a = tile t) ----
    {
      size_t base = (size_t)(t*16 + prow)*HID + pch;
      if (doApply){
        #pragma unroll
        for (int j = 0; j < 4; ++j){
          float tv = b2f((u16)ga[j])*sc0[j] + sh0[j];
          tv = (tv > 0.f) ? tv : 0.f;
          ha[j] = (short)f2b(b2f((u16)ha[j]) + tv);
        }
        #pragma unroll
        for (int j = 0; j < 4; ++j){
          float tv = b2f((u16)ga[4+j])*sc1[j] + sh1[j];
          tv = (tv > 0.f) ? tv : 0.f;
          ha[4+j] = (short)f2b(b2f((u16)ha[4+j]) + tv);
        }
        *(short8*)(h + base) = ha;   // fire-and-forget writeback (rows uniquely owned)
      }
      *(short8*)(&hA[p][prow*LDSROW + pch]) = ha;
    }

    // ---- issue loads for tile t+2G (2 tiles ahead; in flight across 2 barriers) ----
    int t2 = t + 2*G;
    short8 hc = hb, gc = gb;
    if (t2 < NROWT){
      size_t nbase = (size_t)(t2*16 + prow)*HID + pch;
      hc = *(const short8*)(h + nbase);
      if (doApply) gc = *(const short8*)(gout + nbase);
    }

    // ---- barrier: LDS-visibility only (no vmcnt drain) ----
    asm volatile("s_waitcnt lgkmcnt(0)" ::: "memory");
    __builtin_amdgcn_s_barrier();

    // ---- compute: A frags from LDS, MFMA (operands swapped), stores ----
    short8 A[8];
    #pragma unroll
    for (int ks = 0; ks < 8; ++ks)
      A[ks] = *(const short8*)(&hA[p][m*LDSROW + ks*32 + quad*8]);

    f32x4 acc0 = (f32x4){0.f,0.f,0.f,0.f};
    f32x4 acc1 = (f32x4){0.f,0.f,0.f,0.f};
    #pragma unroll
    for (int ks = 0; ks < 8; ++ks){
      acc0 = __builtin_amdgcn_mfma_f32_16x16x32_bf16(B[0][ks], A[ks], acc0, 0, 0, 0);
      acc1 = __builtin_amdgcn_mfma_f32_16x16x32_bf16(B[1][ks], A[ks], acc1, 0, 0, 0);
    }

    int node = t*16 + m;   // D col = node (swapped layout)

    // fused scores: wave 0, VA tile; D row = score col, D col = node. PRE-SCALED by log2e.
    if (wave == 0){
      f32x4 acc5 = (f32x4){0.f,0.f,0.f,0.f};
      #pragma unroll
      for (int ks = 0; ks < 8; ++ks)
        acc5 = __builtin_amdgcn_mfma_f32_16x16x32_bf16(B5[ks], A[ks], acc5, 0, 0, 0);
      #pragma unroll
      for (int r = 0; r < 4; ++r){
        int c = quad*4 + r;            // score column
        float val = acc5[r] * LOG2E;
        if (H == 8){
          int hidx = c >> 1;
          if ((c & 1) == 0) ssrc[node*8 + hidx] = val;
          else              sdst[node*8 + hidx] = val;
        } else {
          if (c == 0)      ssrc[node] = val;
          else if (c == 1) sdst[node] = val;
        }
      }
    }

    // hh store: lane holds 4 consecutive channels for its node -> u16x4 per tile-col
    {
      int ch0 = (wave*2 + 0)*16 + quad*4;
      int ch1 = (wave*2 + 1)*16 + quad*4;
      u16x4 o0, o1;
      #pragma unroll
      for (int r = 0; r < 4; ++r){ o0[r] = f2b(acc0[r]); o1[r] = f2b(acc1[r]); }
      *(u16x4*)(hh + (size_t)node*HID + ch0) = o0;
      *(u16x4*)(hh + (size_t)node*HID + ch1) = o1;
    }

    if (t + G >= NROWT) break;
    t += G; p ^= 1;
    ha = hb; ga = gb;     // rotate register sets
    hb = hc; gb = gc;
  }
}

// ---------------- attention core (Tier B single-node form, 64 lanes x 4 ch) ----------------
// Softmax without max-subtraction (shift-invariant; scores O(few), pre-scaled by log2e).
// Scalar rolling pipeline: index 2-ahead, row/score 1-ahead.
template<int H>
__device__ __forceinline__ void attn_node(int n, int lane, int beg, int end,
    const u16* __restrict__ hh, const float* __restrict__ ssrc,
    const float* __restrict__ sdst, const int* __restrict__ ssorted, float r[4]){
  const u32 f0 = (u32)lane*4u;
  const int hl = (H == 8) ? (lane >> 3) : 0;
  if (beg < 0) beg = 0;
  if (end > E_TOT) end = E_TOT;
  r[0] = r[1] = r[2] = r[3] = 0.f;
  if (beg >= end) return;
  float sd = sdst[(u32)n*H + hl];
  const int last = end - 1;

  // prologue: current edge (beg) fully issued; next index fetched
  int s0 = ssorted[beg];
  s0 = ((unsigned)s0 < N_NODESC) ? s0 : n;
  u16x4 v0 = *(const u16x4*)(hh + (u32)s0*HID + f0);
  float e0 = ssrc[(u32)s0*H + hl];
  int s1 = ssorted[min(beg+1, last)];

  float lval = 0.f, o0 = 0.f, o1 = 0.f, o2 = 0.f, o3 = 0.f;
  for (int i = beg; i < end; ++i){
    int s2 = ssorted[min(i+2, last)];                     // index 2-ahead
    int g1 = ((unsigned)s1 < N_NODESC) ? s1 : n;          // guard 1-ahead
    u16x4 v1 = *(const u16x4*)(hh + (u32)g1*HID + f0);    // row 1-ahead
    float e1 = ssrc[(u32)g1*H + hl];
    // compute current edge
    float ev = e0 + sd;
    ev = fmaxf(fmaxf(ev, NEG_SLOPE*ev), -87.f);   // leaky-relu + underflow guard (v_max3)
    ev = fminf(ev, 87.f);                          // overflow/NaN guard
    float wv = fexp2(ev);
    lval += wv;
    o0 += wv*b2f(v0[0]);
    o1 += wv*b2f(v0[1]);
    o2 += wv*b2f(v0[2]);
    o3 += wv*b2f(v0[3]);
    v0 = v1; e0 = e1; s1 = s2;
  }
  float inv = (lval > 0.f) ? 1.f/lval : 0.f;
  r[0] = o0*inv; r[1] = o1*inv; r[2] = o2*inv; r[3] = o3*inv;
}

// ---------------- Tier A paired attention: wave = 2 consecutive nodes ----------------
// Lanes 0-31 own node 2p (8 ch each, u16x8 rows), lanes 32-63 own node 2p+1.
// R11: rows 2-AHEAD per chain (indices 3-ahead) -> 2 row loads in flight per chain,
// halving the exposed per-edge gather latency if the kernel is latency-bound.
// Loop runs max(degA,degB), tail-masked per half; one 3-int soff read per pair.
template<int H>
__device__ __forceinline__ void attn_gout_loop2(const u16* __restrict__ hh,
    const float* __restrict__ ssrc, const float* __restrict__ sdst,
    const int* __restrict__ soff, const int* __restrict__ ssorted,
    u16* __restrict__ gout, float s[8], float q[8]){
  int tid = threadIdx.x;
  int wid = tid >> 6, lane = tid & 63;
  int half = lane >> 5, l5 = lane & 31;
  const u32 c0 = (u32)l5*8u;
  const int hl = (H == 8) ? (l5 >> 2) : 0;
  int pw = blockIdx.x*4 + wid;
  const int npw = gridDim.x*4;
  // prologue: soff triple for first pair
  int sA = 0, sM = 0, sE = 0;
  if (pw < NPAIR){
    int n0 = pw*2;
    sA = soff[n0]; sM = soff[n0+1]; sE = soff[n0+2];
  }
  for (; pw < NPAIR; pw += npw){
    int n = pw*2 + half;
    // lookahead: next pair's soff triple
    int pw2 = pw + npw;
    int tA = 0, tM = 0, tE = 0;
    if (pw2 < NPAIR){
      int m0 = pw2*2;
      tA = soff[m0]; tM = soff[m0+1]; tE = soff[m0+2];
    }
    int beg   = half ? sM : sA;
    int myDeg = half ? (sE - sM) : (sM - sA);
    int dmax  = max(sM - sA, sE - sM);
    if (myDeg < 0) myDeg = 0;
    int dM1 = (myDeg > 0) ? (myDeg - 1) : 0;
    float sd = sdst[(u32)n*H + hl];

    float lval = 0.f;
    float o0=0.f,o1=0.f,o2=0.f,o3=0.f,o4=0.f,o5=0.f,o6=0.f,o7=0.f;
    if (dmax > 0){
      // prologue: edges 0 and 1 fully issued (2 rows in flight), edge-2 index fetched
      int ad0 = min(beg, E_TOT-1);
      int s0 = ssorted[ad0];
      s0 = ((unsigned)s0 < N_NODESC) ? s0 : n;
      u16x8 v0 = *(const u16x8*)(hh + (u32)s0*HID + c0);
      float e0 = ssrc[(u32)s0*H + hl];
      int s1r = ssorted[min(beg + min(1, dM1), E_TOT-1)];
      int g1 = ((unsigned)s1r < N_NODESC) ? s1r : n;
      u16x8 v1 = *(const u16x8*)(hh + (u32)g1*HID + c0);
      float e1 = ssrc[(u32)g1*H + hl];
      int s2r = ssorted[min(beg + min(2, dM1), E_TOT-1)];
      for (int d = 0; d < dmax; ++d){
        int s3r = ssorted[min(beg + min(d+3, dM1), E_TOT-1)];   // index 3-ahead
        int g2 = ((unsigned)s2r < N_NODESC) ? s2r : n;           // guard 2-ahead
        u16x8 v2 = *(const u16x8*)(hh + (u32)g2*HID + c0);       // row 2-ahead
        float e2 = ssrc[(u32)g2*H + hl];
        float ev = e0 + sd;
        ev = fmaxf(fmaxf(ev, NEG_SLOPE*ev), -87.f);   // leaky-relu + underflow guard
        ev = fminf(ev, 87.f);                          // overflow/NaN guard
        float wv = fexp2(ev);
        wv = (d < myDeg) ? wv : 0.f;                   // per-half tail mask
        lval += wv;
        o0 += wv*b2f(v0[0]); o1 += wv*b2f(v0[1]);
        o2 += wv*b2f(v0[2]); o3 += wv*b2f(v0[3]);
        o4 += wv*b2f(v0[4]); o5 += wv*b2f(v0[5]);
        o6 += wv*b2f(v0[6]); o7 += wv*b2f(v0[7]);
        v0 = v1; e0 = e1;
        v1 = v2; e1 = e2;
        s2r = s3r;
      }
    }
    float inv = (lval > 0.f) ? 1.f/lval : 0.f;
    float r0=o0*inv, r1=o1*inv, r2=o2*inv, r3=o3*inv;
    float r4=o4*inv, r5=o5*inv, r6=o6*inv, r7=o7*inv;
    u16x8 og;
    og[0]=f2b(r0); og[1]=f2b(r1); og[2]=f2b(r2); og[3]=f2b(r3);
    og[4]=f2b(r4); og[5]=f2b(r5); og[6]=f2b(r6); og[7]=f2b(r7);
    *(u16x8*)(gout + (u32)n*HID + c0) = og;
    s[0]+=r0; s[1]+=r1; s[2]+=r2; s[3]+=r3;
    s[4]+=r4; s[5]+=r5; s[6]+=r6; s[7]+=r7;
    q[0]+=r0*r0; q[1]+=r1*r1; q[2]+=r2*r2; q[3]+=r3*r3;
    q[4]+=r4*r4; q[5]+=r5*r5; q[6]+=r6*r6; q[7]+=r7*r7;
    sA = tA; sM = tM; sE = tE;
  }
}

__global__ __launch_bounds__(256) void k_attn_gout(const u16* __restrict__ hh,
    const float* __restrict__ ssrc, const float* __restrict__ sdst,
    const int* __restrict__ soff, const int* __restrict__ ssorted,
    u16* __restrict__ gout, int H, float* __restrict__ bnpart){
  __shared__ float lsum[4*512];   // [wave][lane*8+j]; lane<32 -> ch c, lane>=32 -> 256+ch
  __shared__ float lsq [4*512];
  int tid = threadIdx.x, wid = tid >> 6, lane = tid & 63;
  float s[8] = {0.f,0.f,0.f,0.f,0.f,0.f,0.f,0.f};
  float q[8] = {0.f,0.f,0.f,0.f,0.f,0.f,0.f,0.f};
  if (H == 8) attn_gout_loop2<8>(hh, ssrc, sdst, soff, ssorted, gout, s, q);
  else        attn_gout_loop2<1>(hh, ssrc, sdst, soff, ssorted, gout, s, q);
  #pragma unroll
  for (int j = 0; j < 8; ++j){
    lsum[wid*512 + lane*8 + j] = s[j];
    lsq [wid*512 + lane*8 + j] = q[j];
  }
  __syncthreads();
  int c = tid;
  float ts = 0.f, tq = 0.f;
  #pragma unroll
  for (int w = 0; w < 4; ++w){
    ts += lsum[w*512 + c] + lsum[w*512 + 256 + c];
    tq += lsq [w*512 + c] + lsq [w*512 + 256 + c];
  }
  float* prow = bnpart + (size_t)(blockIdx.x & (NPART-1))*512;
  atomicAdd(&prow[c], ts);
  atomicAdd(&prow[HID + c], tq);
}

// Tier B pass 1: recompute attention, block-reduce BN stats into partials
template<int H>
__device__ __forceinline__ void attn_stats_loop(const u16* __restrict__ hh,
    const float* __restrict__ ssrc, const float* __restrict__ sdst,
    const int* __restrict__ soff, const int* __restrict__ ssorted,
    float s[4], float q[4]){
  int wid = threadIdx.x >> 6, lane = threadIdx.x & 63;
  int gw = blockIdx.x*4 + wid;
  int nw = gridDim.x*4;
  int beg = 0, end = 0;
  if (gw < N_NODESC){ beg = soff[gw]; end = soff[gw+1]; }
  for (int n = gw; n < N_NODESC; n += nw){
    int n2 = n + nw;
    int pb = 0, pe = 0;
    if (n2 < N_NODESC){ pb = soff[n2]; pe = soff[n2+1]; }
    float r[4];
    attn_node<H>(n, lane, beg, end, hh, ssrc, sdst, ssorted, r);
    #pragma unroll
    for (int j = 0; j < 4; ++j){ s[j] += r[j]; q[j] += r[j]*r[j]; }
    beg = pb; end = pe;
  }
}

__global__ __launch_bounds__(256) void k_attn_stats(const u16* __restrict__ hh,
    const float* __restrict__ ssrc, const float* __restrict__ sdst,
    const int* __restrict__ soff, const int* __restrict__ ssorted,
    float* __restrict__ bnpart, int H){
  __shared__ float lsum[4*HID];
  __shared__ float lsq[4*HID];
  int wid = threadIdx.x >> 6, lane = threadIdx.x & 63;
  float s[4] = {0.f,0.f,0.f,0.f}, q[4] = {0.f,0.f,0.f,0.f};
  if (H == 8) attn_stats_loop<8>(hh, ssrc, sdst, soff, ssorted, s, q);
  else        attn_stats_loop<1>(hh, ssrc, sdst, soff, ssorted, s, q);
  int f0 = lane*4;
  #pragma unroll
  for (int j = 0; j < 4; ++j){ lsum[wid*HID + f0 + j] = s[j]; lsq[wid*HID + f0 + j] = q[j]; }
  __syncthreads();
  int c = threadIdx.x;
  float ts = lsum[c] + lsum[HID+c] + lsum[2*HID+c] + lsum[3*HID+c];
  float tq = lsq[c]  + lsq[HID+c]  + lsq[2*HID+c]  + lsq[3*HID+c];
  float* prow = bnpart + (size_t)(blockIdx.x & (NPART-1))*512;
  atomicAdd(&prow[c], ts);
  atomicAdd(&prow[HID + c], tq);
}

// Tier B pass 2: recompute attention, fused BN+ReLU+residual into h
__global__ __launch_bounds__(256) void k_attn_apply(const u16* __restrict__ hh,
    const float* __restrict__ ssrc, const float* __restrict__ sdst,
    const int* __restrict__ soff, const int* __restrict__ ssorted,
    const float* __restrict__ scale, const float* __restrict__ shift,
    u16* __restrict__ h, int H){
  int wid = threadIdx.x >> 6, lane = threadIdx.x & 63;
  int n = blockIdx.x*4 + wid;
  if (n >= N_NODESC) return;
  int beg = soff[n], end = soff[n+1];
  float r[4];
  if (H == 8) attn_node<8>(n, lane, beg, end, hh, ssrc, sdst, ssorted, r);
  else        attn_node<1>(n, lane, beg, end, hh, ssrc, sdst, ssorted, r);
  int f0 = lane*4;
  const f32x4 sc = *(const f32x4*)(scale + f0);
  const f32x4 sh = *(const f32x4*)(shift + f0);
  u16x4 hv = *(u16x4*)(h + (size_t)n*HID + f0);
  u16x4 o;
  #pragma unroll
  for (int j = 0; j < 4; ++j){
    float t = r[j]*sc[j] + sh[j];
    t = (t > 0.f) ? t : 0.f;
    o[j] = f2b(b2f(hv[j]) + t);
  }
  *(u16x4*)(h + (size_t)n*HID + f0) = o;
}

// ---------------- BN finalize: reduce 64 partial rows -> scale/shift ----------------
__global__ __launch_bounds__(256) void k_bn_final(const float* __restrict__ bnpart,
    const void* __restrict__ gamma, const void* __restrict__ beta,
    float* __restrict__ scale, float* __restrict__ shift,
    const int* __restrict__ flagp, int loff){
  int f = *flagp;
  int c = threadIdx.x;
  float s = 0.f, q = 0.f;
  #pragma unroll 4
  for (int p = 0; p < NPART; ++p){
    s += bnpart[(size_t)p*512 + c];
    q += bnpart[(size_t)p*512 + HID + c];
  }
  float mu  = s * (1.f/N_NODESC);
  float var = q * (1.f/N_NODESC) - mu*mu;
  if (!(var >= 0.f)) var = 0.f;   // also catches NaN
  float sc = ldp(gamma, (size_t)loff + c, f) * rsqrtf(var + BN_EPSC);
  scale[c] = sc;
  shift[c] = ldp(beta, (size_t)loff + c, f) - mu*sc;
}

// ---------------- mean pool per graph (Tier B; batch sorted, counts fused) ----------------
__global__ __launch_bounds__(256) void k_pool(const u16* __restrict__ h,
    const int* __restrict__ batch, float* __restrict__ gsum, int* __restrict__ gcnt){
  int c = threadIdx.x;
  int r0 = blockIdx.x * 256;
  int r1 = min(r0 + 256, N_NODESC);
  if (r0 >= N_NODESC) return;
  int cur = batch[r0];
  float acc = 0.f;
  int nacc = 0;
  for (int r = r0; r < r1; ++r){
    int b = batch[r];
    if ((unsigned)b >= NGRAPHS) continue;
    if (b != cur){
      if ((unsigned)cur < NGRAPHS){
        atomicAdd(&gsum[cur*HID + c], acc);
        if (c == 0) atomicAdd(&gcnt[cur], nacc);
      }
      acc = 0.f; nacc = 0; cur = b;
    }
    acc += b2f(h[(size_t)r*HID + c]);
    nacc++;
  }
  if ((unsigned)cur < NGRAPHS){
    atomicAdd(&gsum[cur*HID + c], acc);
    if (c == 0) atomicAdd(&gcnt[cur], nacc);
  }
}

// Tier A: pool fused with last layer's BN+ReLU+residual.
__global__ __launch_bounds__(256) void k_pool_fused(const u16* __restrict__ h,
    const u16* __restrict__ gout, const float* __restrict__ scale, const float* __restrict__ shift,
    const int* __restrict__ batch, float* __restrict__ gsum, int* __restrict__ gcnt){
  __shared__ int lb[64];
  int tid = threadIdx.x;
  int r0 = blockIdx.x*64;
  if (tid < 64){
    int rr = r0 + tid;
    lb[tid] = (rr < N_NODESC) ? batch[rr] : -1;
  }
  __syncthreads();
  int wid = tid >> 6, lane = tid & 63;
  int c4 = lane*4;
  const f32x4 sc = *(const f32x4*)(scale + c4);
  const f32x4 sh = *(const f32x4*)(shift + c4);
  int rbase = r0 + wid*16;
  f32x4 acc = (f32x4){0.f,0.f,0.f,0.f};
  int nacc = 0, cur = -1;
  #pragma unroll 4
  for (int k = 0; k < 16; ++k){
    int r = rbase + k;
    if (r >= N_NODESC) break;
    int b = lb[wid*16 + k];
    if ((unsigned)b >= NGRAPHS) continue;
    if (b != cur){
      if ((unsigned)cur < NGRAPHS){
        atomicAdd(&gsum[cur*HID + c4+0], acc[0]);
        atomicAdd(&gsum[cur*HID + c4+1], acc[1]);
        atomicAdd(&gsum[cur*HID + c4+2], acc[2]);
        atomicAdd(&gsum[cur*HID + c4+3], acc[3]);
        if (lane == 0) atomicAdd(&gcnt[cur], nacc);
      }
      acc = (f32x4){0.f,0.f,0.f,0.f}; nacc = 0; cur = b;
    }
    const u16x4 hv = *(const u16x4*)(h    + (size_t)r*HID + c4);
    const u16x4 gv = *(const u16x4*)(gout + (size_t)r*HID + c4);
    #pragma unroll
    for (int j = 0; j < 4; ++j){
      float t = b2f(gv[j])*sc[j] + sh[j];
      t = (t > 0.f) ? t : 0.f;
      acc[j] += b2f(hv[j]) + t;
    }
    nacc++;
  }
  if ((unsigned)cur < NGRAPHS){
    atomicAdd(&gsum[cur*HID + c4+0], acc[0]);
    atomicAdd(&gsum[cur*HID + c4+1], acc[1]);
    atomicAdd(&gsum[cur*HID + c4+2], acc[2]);
    atomicAdd(&gsum[cur*HID + c4+3], acc[3]);
    if (lane == 0) atomicAdd(&gcnt[cur], nacc);
  }
}

// ---------------- G prep: mean-divide and convert to bf16 (64 KB, L2-resident) ----------------
__global__ __launch_bounds__(256) void k_gprep(const float* __restrict__ gsum,
    const int* __restrict__ gcnt, u16* __restrict__ gbf){
  int g = blockIdx.x, c = threadIdx.x;
  int cc = gcnt[g]; if (cc < 1) cc = 1;
  gbf[g*HID + c] = f2b(gsum[(size_t)g*HID + c] * (1.f/(float)cc));
}

// ---------------- token predictors: MFMA GEMM  preds[s] = G[128,256] @ W_s[256,5002] ----------------
__global__ __launch_bounds__(256) void k_pred(const u16* __restrict__ gbf,
    const void* __restrict__ tokW, const void* __restrict__ tokb, void* __restrict__ out,
    const int* __restrict__ flagp){
  int f = *flagp;
  int wave = threadIdx.x >> 6, lane = threadIdx.x & 63;
  int m = lane & 15, quad = lane >> 4;
  int s = blockIdx.y;
  int v = blockIdx.x*64 + wave*16 + m;       // this lane's vocab column
  bool vok = (v < VOCABC);

  f32x4 acc[8];
  #pragma unroll
  for (int t = 0; t < 8; ++t) acc[t] = (f32x4){0.f,0.f,0.f,0.f};

  const size_t wrow = (size_t)s*HID*VOCABC + v;
  #pragma unroll
  for (int ks = 0; ks < 8; ++ks){
    int kb = ks*32 + quad*8;
    short8 b;
    #pragma unroll
    for (int j = 0; j < 8; ++j)
      b[j] = vok ? (short)f2b(ldp(tokW, wrow + (size_t)(kb + j)*VOCABC, f)) : (short)0;
    #pragma unroll
    for (int t = 0; t < 8; ++t){
      const short8 a = *(const short8*)(gbf + (size_t)(t*16 + m)*HID + kb);
      acc[t] = __builtin_amdgcn_mfma_f32_16x16x32_bf16(a, b, acc[t], 0, 0, 0);
    }
  }

  float bb = vok ? ldp(tokb, (size_t)s*VOCABC + v, f) : 0.f;
  if (!vok) return;
  #pragma unroll
  for (int t = 0; t < 8; ++t){
    #pragma unroll
    for (int r = 0; r < 4; ++r){
      int grow = t*16 + quad*4 + r;
      float val = acc[t][r] + bb;
      size_t oi = ((size_t)(s*NGRAPHS + grow)*VOCABC) + v;
      if (f) ((float*)out)[oi] = val;
      else   ((u16*)out)[oi]   = f2b(val);
    }
  }
}

// ---------------- host launcher ----------------
extern "C" void kernel_launch(void* const* d_in, const int* in_sizes, int n_in,
                              void* d_out, int out_size, void* d_ws, size_t ws_size,
                              hipStream_t stream) {
  const int* x          = (const int*)d_in[0];
  const int* node_depth = (const int*)d_in[1];
  const int* edge_index = (const int*)d_in[2];
  const int* batch      = (const int*)d_in[3];
  const void* type_emb  = d_in[4];
  const void* attr_emb  = d_in[5];
  const void* depth_emb = d_in[6];
  const void* Ws        = d_in[7];
  const void* att_src   = d_in[8];
  const void* att_dst   = d_in[9];
  // d_in[10] = gat_bias: dropped (constant per channel cancels inside BatchNorm)
  const void* bn_gamma  = d_in[11];
  const void* bn_beta   = d_in[12];
  const void* tok_W     = d_in[13];
  const void* tok_b     = d_in[14];

  // ---- workspace carve ----
  char* base = (char*)d_ws;
  size_t off = 0;
  auto carve = [&](size_t bytes) -> void* {
    void* p = base + off;
    off += (bytes + 255) & ~(size_t)255;
    return p;
  };
  u16*   h     = (u16*)carve((size_t)N_NODESC*HID*2);     // 51.2 MB
  u16*   hh    = (u16*)carve((size_t)N_NODESC*HID*2);     // 51.2 MB
  float* ssrc  = (float*)carve((size_t)N_NODESC*8*4);     // 3.2 MB
  float* sdst  = (float*)carve((size_t)N_NODESC*8*4);     // 3.2 MB
  int*   soff  = (int*)carve((size_t)(N_NODESC+1)*4);
  int*   cursor= (int*)carve((size_t)N_NODESC*4);
  int*   ssorted=(int*)carve((size_t)E_TOT*4);            // 2.0 MB
  int*   btot  = (int*)carve((size_t)NCHUNK*4);
  int*   boff  = (int*)carve((size_t)NCHUNK*4);
  u16*   WT    = (u16*)carve((size_t)NLAYERS*HID*HID*2);  // 0.5 MB
  u16*   VAT   = (u16*)carve((size_t)NLAYERS*16*HID*2);   // 32 KB fused-score matrices
  float* bnpart= (float*)carve((size_t)NPART*512*4);      // 128 KB BN partials
  float* bnscale=(float*)carve(HID*4);
  float* bnshift=(float*)carve(HID*4);
  float* gsum  = (float*)carve((size_t)NGRAPHS*HID*4);    // 128 KB
  int*   gcnt  = (int*)carve((size_t)NGRAPHS*4);          // adjacent to gsum
  u16*   gbf   = (u16*)carve((size_t)NGRAPHS*HID*2);      // 64 KB bf16 pooled graphs
  int*   dflag = (int*)carve(256);
  size_t common = off;
  u16*   gout  = (u16*)carve((size_t)N_NODESC*HID*2);     // +51.2 MB
  const bool useGout = (off <= ws_size);
  if (common > ws_size) return;  // cannot run at all

  const int EB  = (E_TOT + 255)/256;
  const int NB4 = (N_NODESC + 3)/4;      // wave-per-node kernels

  // dtype detection first
  k_detect<<<1, 64, 0, stream>>>(type_emb, dflag);

  // setup (k_embed also zeroes cursor; k_prep = transW + prepVA fused)
  k_embed<<<NCH64, 256, 0, stream>>>(x, node_depth, type_emb, attr_emb, depth_emb, h, dflag, cursor);
  k_prep<<<256*NLAYERS + NLAYERS, 256, 0, stream>>>(Ws, WT, att_src, att_dst, VAT, dflag);
  k_hist<<<EB, 256, 0, stream>>>(edge_index, cursor);
  k_scan_part<<<NCHUNK, 256, 0, stream>>>(cursor, soff, btot);
  k_scan_tot<<<1, 256, 0, stream>>>(btot, boff, soff + N_NODESC);
  k_scan_add<<<NCHUNK, 256, 0, stream>>>(soff, boff, cursor);   // also zeroes cursor
  k_scatter<<<EB, 256, 0, stream>>>(edge_index, soff, cursor, ssorted);

  // layers — Tier A: bn_apply of layer l-1 and scores fused into gemm of layer l
  for (int l = 0; l < NLAYERS; ++l){
    int H = (l == NLAYERS-1) ? 1 : 8;
    int doApply = (useGout && l > 0) ? 1 : 0;
    k_gemm<<<GEMMB, 512, 0, stream>>>(h, gout, bnscale, bnshift, doApply,
                                     WT + (size_t)l*HID*HID, VAT + (size_t)l*16*HID,
                                     hh, ssrc, sdst, H, bnpart);
    if (useGout){
      k_attn_gout<<<ATTNB, 256, 0, stream>>>(hh, ssrc, sdst, soff, ssorted, gout, H, bnpart);
      k_bn_final<<<1, 256, 0, stream>>>(bnpart, bn_gamma, bn_beta, bnscale, bnshift, dflag, l*HID);
    } else {
      k_attn_stats<<<2048, 256, 0, stream>>>(hh, ssrc, sdst, soff, ssorted, bnpart, H);
      k_bn_final<<<1, 256, 0, stream>>>(bnpart, bn_gamma, bn_beta, bnscale, bnshift, dflag, l*HID);
      k_attn_apply<<<NB4, 256, 0, stream>>>(hh, ssrc, sdst, soff, ssorted, bnscale, bnshift, h, H);
    }
  }

  // pool (gsum+gcnt adjacent -> single zero launch)
  k_zero<<<(NGRAPHS*HID + NGRAPHS + 255)/256, 256, 0, stream>>>((int*)gsum, NGRAPHS*HID + NGRAPHS);
  if (useGout)
    k_pool_fused<<<NCH64, 256, 0, stream>>>(h, gout, bnscale, bnshift, batch, gsum, gcnt);
  else
    k_pool<<<NCHUNK, 256, 0, stream>>>(h, batch, gsum, gcnt);
  k_gprep<<<NGRAPHS, 256, 0, stream>>>(gsum, gcnt, gbf);

  // predictors (MFMA GEMM)
  k_pred<<<dim3(NVQ, SEQLEN), 256, 0, stream>>>(gbf, tok_W, tok_b, d_out, dflag);
}

// Round 12
// 699.174 us; speedup vs baseline: 1.0101x; 1.0101x over previous
//
#include <hip/hip_runtime.h>
#include <stdint.h>

typedef uint16_t u16;
typedef uint32_t u32;

#define N_NODESC 100000
#define N_EDGESC 400000
#define E_TOT    500000   // edges + self loops
#define HID      256
#define NLAYERS  4
#define NGRAPHS  128
#define SEQLEN   5
#define VOCABC   5002
#define MAXDEPTH 20
#define NEG_SLOPE 0.2f
#define BN_EPSC  1e-5f
#define LOG2E    1.4426950408889634f
#define NCHUNK   ((N_NODESC + 255)/256)   // 391
#define NCH64    ((N_NODESC + 63)/64)     // 1563 (64-row chunks)
#define NROWT    (N_NODESC/16)            // 6250 row tiles, exact
#define NPAIR    (N_NODESC/2)             // 50000 node pairs for paired attention
#define NPART    64                       // BN partial rows (each 512 floats: 256 sum + 256 sq)
#define NVQ      ((VOCABC + 63)/64)       // 79 vocab quads for k_pred
#define ATTNB    2048                     // grid for k_attn_gout
#define GEMMB    512                      // grid for k_gemm (~12 tiles/block, 2-deep pipeline)
#define LDSROW   264                      // padded LDS row (u16): 2-way alias only

typedef __attribute__((ext_vector_type(8))) short short8;
typedef __attribute__((ext_vector_type(4))) float f32x4;
typedef __attribute__((ext_vector_type(4))) unsigned short u16x4;
typedef __attribute__((ext_vector_type(8))) unsigned short u16x8;

__device__ __forceinline__ float b2f(u16 u){
  union { u32 i; float f; } v; v.i = ((u32)u) << 16; return v.f;
}
__device__ __forceinline__ u16 f2b(float f){
  union { float f; u32 i; } v; v.f = f;
  u32 u = v.i;
  u += 0x7FFFu + ((u >> 16) & 1u);   // RNE
  return (u16)(u >> 16);
}
// raw v_exp_f32 (exp2). s_nop covers the trans-op -> dependent-VALU wait state.
__device__ __forceinline__ float fexp2(float x){
  float r;
  asm("v_exp_f32 %0, %1\n\ts_nop 0" : "=v"(r) : "v"(x));
  return r;
}
// dual-dtype parameter load: flag=1 -> f32, flag=0 -> bf16
__device__ __forceinline__ float ldp(const void* p, size_t i, int f){
  return f ? ((const float*)p)[i] : b2f(((const u16*)p)[i]);
}
// 4-wide dual-dtype load (i must be 4-element aligned)
__device__ __forceinline__ f32x4 ld4(const void* p, size_t i, int f){
  f32x4 r;
  if (f){
    r = *(const f32x4*)((const float*)p + i);
  } else {
    const u16x4 u = *(const u16x4*)((const u16*)p + i);
    r[0] = b2f(u[0]); r[1] = b2f(u[1]); r[2] = b2f(u[2]); r[3] = b2f(u[3]);
  }
  return r;
}

// ---------------- dtype detector: sample type_emb both ways ----------------
__global__ __launch_bounds__(64) void k_detect(const void* temb, int* flag){
  int lane = threadIdx.x;
  const u32* w32 = (const u32*)temb;
  int sf = 0, sb = 0;
  for (int i = lane; i < 256; i += 64){
    u32 w = w32[i];
    union { u32 u; float f; } cf; cf.u = w;
    float af = fabsf(cf.f);
    if (cf.f == 0.0f || (af >= 1e-12f && af <= 4096.f)) sf++;
    float b0 = b2f((u16)(w & 0xFFFFu));
    float b1 = b2f((u16)(w >> 16));
    float a0 = fabsf(b0), a1 = fabsf(b1);
    if (b0 == 0.f || (a0 >= 1e-12f && a0 <= 4096.f)) sb++;
    if (b1 == 0.f || (a1 >= 1e-12f && a1 <= 4096.f)) sb++;
  }
  #pragma unroll
  for (int o = 1; o < 64; o <<= 1){ sf += __shfl_xor(sf, o); sb += __shfl_xor(sb, o); }
  if (lane == 0) *flag = (2*sf > sb) ? 1 : 0;
}

// ---------------- utility ----------------
__global__ __launch_bounds__(256) void k_zero(int* __restrict__ p, int n){
  int i = blockIdx.x*256 + threadIdx.x;
  if (i < n) p[i] = 0;
}

// ---------------- embedding: 64-node chunks, lane owns 4 channels; zeroes cursor ----------------
__global__ __launch_bounds__(256) void k_embed(const int* __restrict__ x, const int* __restrict__ nd,
    const void* __restrict__ temb, const void* __restrict__ aemb, const void* __restrict__ demb,
    u16* __restrict__ h, const int* __restrict__ flagp, int* __restrict__ cursor){
  int f = *flagp;
  int tid = threadIdx.x;
  int r0 = blockIdx.x*64;
  if (tid < 64 && r0 + tid < N_NODESC) cursor[r0 + tid] = 0;
  int wid = tid >> 6, lane = tid & 63;
  int c4 = lane*4;
  #pragma unroll 4
  for (int k = 0; k < 16; ++k){
    int n = r0 + wid*16 + k;
    if (n >= N_NODESC) break;
    int t = x[n*2+0], a = x[n*2+1];
    if (t < 0) t = 0; if (t > 97) t = 97;
    if (a < 0) a = 0; if (a > 10029) a = 10029;
    int d = nd[n]; if (d > MAXDEPTH) d = MAXDEPTH; if (d < 0) d = 0;
    const f32x4 vt = ld4(temb, (size_t)t*HID + c4, f);
    const f32x4 va = ld4(aemb, (size_t)a*HID + c4, f);
    const f32x4 vd = ld4(demb, (size_t)d*HID + c4, f);
    u16x4 o;
    #pragma unroll
    for (int j = 0; j < 4; ++j) o[j] = f2b(vt[j] + va[j] + vd[j]);
    *(u16x4*)(h + (size_t)n*HID + c4) = o;
  }
}

// ---------------- edge sort by dst (counting sort) ----------------
__global__ __launch_bounds__(256) void k_hist(const int* __restrict__ ei, int* __restrict__ cnt){
  int e = blockIdx.x*256 + threadIdx.x;
  if (e >= E_TOT) return;
  int dst = (e < N_EDGESC) ? ei[N_EDGESC + e] : (e - N_EDGESC);
  if ((unsigned)dst >= N_NODESC) return;
  atomicAdd(&cnt[dst], 1);
}

// hierarchical scan, phase 1: per-256-chunk exclusive scan + chunk total
__global__ __launch_bounds__(256) void k_scan_part(const int* __restrict__ cnt,
    int* __restrict__ off, int* __restrict__ btot){
  __shared__ int lds[256];
  int b = blockIdx.x, tid = threadIdx.x;
  int i = b*256 + tid;
  int v = (i < N_NODESC) ? cnt[i] : 0;
  lds[tid] = v;
  __syncthreads();
  #pragma unroll
  for (int s = 1; s < 256; s <<= 1){
    int t = (tid >= s) ? lds[tid - s] : 0;
    __syncthreads();
    lds[tid] += t;
    __syncthreads();
  }
  if (i < N_NODESC) off[i] = lds[tid] - v;   // chunk-local exclusive
  if (tid == 255) btot[b] = lds[255];
}

// phase 2: scan the 391 chunk totals (1 block), write grand total to offN
__global__ __launch_bounds__(256) void k_scan_tot(const int* __restrict__ btot,
    int* __restrict__ boff, int* __restrict__ offN){
  __shared__ int lds[256];
  __shared__ int s_carry;
  int tid = threadIdx.x;
  if (tid == 0) s_carry = 0;
  __syncthreads();
  for (int base = 0; base < NCHUNK; base += 256){
    int i = base + tid;
    int v = (i < NCHUNK) ? btot[i] : 0;
    lds[tid] = v;
    __syncthreads();
    #pragma unroll
    for (int s = 1; s < 256; s <<= 1){
      int t = (tid >= s) ? lds[tid - s] : 0;
      __syncthreads();
      lds[tid] += t;
      __syncthreads();
    }
    if (i < NCHUNK) boff[i] = s_carry + lds[tid] - v;
    __syncthreads();
    if (tid == 255) s_carry += lds[255];
    __syncthreads();
  }
  if (tid == 0) *offN = s_carry;
}

// phase 3: add chunk offsets; also re-zero cursor for the scatter pass
__global__ __launch_bounds__(256) void k_scan_add(int* __restrict__ off,
    const int* __restrict__ boff, int* __restrict__ cursor){
  int b = blockIdx.x;
  int i = b*256 + threadIdx.x;
  if (i < N_NODESC){ off[i] += boff[b]; cursor[i] = 0; }
}

__global__ __launch_bounds__(256) void k_scatter(const int* __restrict__ ei,
    const int* __restrict__ soff, int* __restrict__ cursor, int* __restrict__ ssorted){
  int e = blockIdx.x*256 + threadIdx.x;
  if (e >= E_TOT) return;
  int src = (e < N_EDGESC) ? ei[e]            : (e - N_EDGESC);
  int dst = (e < N_EDGESC) ? ei[N_EDGESC + e] : (e - N_EDGESC);
  if ((unsigned)dst >= N_NODESC || (unsigned)src >= N_NODESC) return;
  int pos = soff[dst] + atomicAdd(&cursor[dst], 1);
  if ((unsigned)pos < E_TOT) ssorted[pos] = src;
}

// ---------------- fused prep: W transpose (blocks 0..1023) + VA precompute (blocks 1024..1027) ----------------
// VA inner loop vectorized 4-wide (was 256 scalar-load iterations -> 64).
__global__ __launch_bounds__(256) void k_prep(const void* __restrict__ W, u16* __restrict__ WT,
    const void* __restrict__ asrc, const void* __restrict__ adst,
    u16* __restrict__ VAT, const int* __restrict__ flagp){
  int f = *flagp;
  int bx = blockIdx.x;
  if (bx < 256*NLAYERS){
    int l = bx >> 8, n2 = bx & 255, k = threadIdx.x;
    WT[(l*HID + n2)*HID + k] = f2b(ldp(W, (size_t)(l*HID + k)*HID + n2, f));
    return;
  }
  int l = bx - 256*NLAYERS;          // 0..NLAYERS-1
  int i = threadIdx.x;               // input channel
  int H = (l == NLAYERS-1) ? 1 : 8;
  float col[16];
  #pragma unroll
  for (int c = 0; c < 16; ++c) col[c] = 0.f;
  const size_t wrow = ((size_t)l*HID + i)*HID;
  const size_t arow = (size_t)l*HID;
  if (H == 8){
    for (int h = 0; h < 8; ++h){
      float vs = 0.f, vd = 0.f;
      for (int o = h*32; o < h*32+32; o += 4){
        f32x4 w = ld4(W, wrow + o, f);
        f32x4 as = ld4(asrc, arow + o, f);
        f32x4 ad = ld4(adst, arow + o, f);
        #pragma unroll
        for (int j = 0; j < 4; ++j){ vs += w[j]*as[j]; vd += w[j]*ad[j]; }
      }
      col[h*2] = vs; col[h*2+1] = vd;
    }
  } else {
    float vs = 0.f, vd = 0.f;
    for (int o = 0; o < HID; o += 4){
      f32x4 w = ld4(W, wrow + o, f);
      f32x4 as = ld4(asrc, arow + o, f);
      f32x4 ad = ld4(adst, arow + o, f);
      #pragma unroll
      for (int j = 0; j < 4; ++j){ vs += w[j]*as[j]; vd += w[j]*ad[j]; }
    }
    col[0] = vs; col[1] = vd;
  }
  #pragma unroll
  for (int c = 0; c < 16; ++c)
    VAT[((size_t)l*16 + c)*HID + i] = f2b(col[c]);
}

// ---------------- GEMM + fused prev-layer BN apply + fused scores (17th B-tile) ----------------
// 8-wave (512-thread) blocks, 2 B-tiles/wave; swapped MFMA operand order (D col=node).
// One raw s_barrier per tile; lgkmcnt-only drain. 2-tile-deep rotating register
// prefetch; grid 512 so each block runs ~12 tiles (pipeline amortized).
__global__ __launch_bounds__(512) void k_gemm(u16* __restrict__ h,
    const u16* __restrict__ gout, const float* __restrict__ scale,
    const float* __restrict__ shift, int doApply,
    const u16* __restrict__ WT, const u16* __restrict__ VAT,
    u16* __restrict__ hh, float* __restrict__ ssrc, float* __restrict__ sdst,
    int H, float* __restrict__ bnpart){
  __shared__ u16 hA[2][16*LDSROW];
  int tid = threadIdx.x;
  if (blockIdx.x < NPART) bnpart[blockIdx.x*512 + tid] = 0.f;
  int wave = tid >> 6, lane = tid & 63;
  int m = lane & 15, quad = lane >> 4;
  int prow = tid >> 5, pch = (tid & 31)*8;   // staging: thread owns (row=prow, ch pch..pch+7)

  // 2 B-tiles per wave (col-tiles wave*2, wave*2+1)
  short8 B[2][8];
  #pragma unroll
  for (int jj = 0; jj < 2; ++jj){
    const u16* wp = WT + (size_t)(((wave*2 + jj)*16 + m)*HID) + quad*8;
    #pragma unroll
    for (int ks = 0; ks < 8; ++ks)
      B[jj][ks] = *(const short8*)(wp + ks*32);
  }
  short8 B5[8];
  if (wave == 0){
    const u16* vp = VAT + (size_t)m*HID + quad*8;
    #pragma unroll
    for (int ks = 0; ks < 8; ++ks)
      B5[ks] = *(const short8*)(vp + ks*32);
  }

  // hoisted BN scale/shift for this thread's 8 channels
  f32x4 sc0 = {}, sc1 = {}, sh0 = {}, sh1 = {};
  if (doApply){
    sc0 = *(const f32x4*)(scale + pch);     sh0 = *(const f32x4*)(shift + pch);
    sc1 = *(const f32x4*)(scale + pch + 4); sh1 = *(const f32x4*)(shift + pch + 4);
  }

  const int G = gridDim.x;
  int t = blockIdx.x;
  if (t >= NROWT) return;     // uniform per block

  // prologue: 2 tiles in flight (sets a=tile t, b=tile t+G)
  short8 ha, ga = {}, hb, gb = {};
  {
    size_t base = (size_t)(t*16 + prow)*HID + pch;
    ha = *(const short8*)(h + base);
    if (doApply) ga = *(const short8*)(gout + base);
  }
  {
    int t1 = t + G;
    if (t1 < NROWT){
      size_t base = (size_t)(t1*16 + prow)*HID + pch;
      hb = *(const short8*)(h + base);
      if (doApply) gb = *(const short8*)(gout + base);
    } else { hb = ha; gb = ga; }
  }

  int p = 0;
  for (;;){
    // ---- stage: BN apply (prev layer) + h writeback + LDS write (set a = tile t) ----
    {
      size_t base = (size_t)(t*16 + prow)*HID + pch;
      if (doApply){
        #pragma unroll
        for (int j = 0; j < 4; ++j){
          float tv = b2f((u16)ga[j])*sc0[j] + sh0[j];
          tv = (tv > 0.f) ? tv : 0.f;
          ha[j] = (short)f2b(b2f((u16)ha[j]) + tv);
        }
        #pragma unroll
        for (int j = 0; j < 4; ++j){
          float tv = b2f((u16)ga[4+j])*sc1[j] + sh1[j];
          tv = (tv > 0.f) ? tv : 0.f;
          ha[4+j] = (short)f2b(b2f((u16)ha[4+j]) + tv);
        }
        *(short8*)(h + base) = ha;   // fire-and-forget writeback (rows uniquely owned)
      }
      *(short8*)(&hA[p][prow*LDSROW + pch]) = ha;
    }

    // ---- issue loads for tile t+2G (2 tiles ahead; in flight across 2 barriers) ----
    int t2 = t + 2*G;
    short8 hc = hb, gc = gb;
    if (t2 < NROWT){
      size_t nbase = (size_t)(t2*16 + prow)*HID + pch;
      hc = *(const short8*)(h + nbase);
      if (doApply) gc = *(const short8*)(gout + nbase);
    }

    // ---- barrier: LDS-visibility only (no vmcnt drain) ----
    asm volatile("s_waitcnt lgkmcnt(0)" ::: "memory");
    __builtin_amdgcn_s_barrier();

    // ---- compute: A frags from LDS, MFMA (operands swapped), stores ----
    short8 A[8];
    #pragma unroll
    for (int ks = 0; ks < 8; ++ks)
      A[ks] = *(const short8*)(&hA[p][m*LDSROW + ks*32 + quad*8]);

    f32x4 acc0 = (f32x4){0.f,0.f,0.f,0.f};
    f32x4 acc1 = (f32x4){0.f,0.f,0.f,0.f};
    #pragma unroll
    for (int ks = 0; ks < 8; ++ks){
      acc0 = __builtin_amdgcn_mfma_f32_16x16x32_bf16(B[0][ks], A[ks], acc0, 0, 0, 0);
      acc1 = __builtin_amdgcn_mfma_f32_16x16x32_bf16(B[1][ks], A[ks], acc1, 0, 0, 0);
    }

    int node = t*16 + m;   // D col = node (swapped layout)

    // fused scores: wave 0, VA tile; D row = score col, D col = node. PRE-SCALED by log2e.
    if (wave == 0){
      f32x4 acc5 = (f32x4){0.f,0.f,0.f,0.f};
      #pragma unroll
      for (int ks = 0; ks < 8; ++ks)
        acc5 = __builtin_amdgcn_mfma_f32_16x16x32_bf16(B5[ks], A[ks], acc5, 0, 0, 0);
      #pragma unroll
      for (int r = 0; r < 4; ++r){
        int c = quad*4 + r;            // score column
        float val = acc5[r] * LOG2E;
        if (H == 8){
          int hidx = c >> 1;
          if ((c & 1) == 0) ssrc[node*8 + hidx] = val;
          else              sdst[node*8 + hidx] = val;
        } else {
          if (c == 0)      ssrc[node] = val;
          else if (c == 1) sdst[node] = val;
        }
      }
    }

    // hh store: lane holds 4 consecutive channels for its node -> u16x4 per tile-col
    {
      int ch0 = (wave*2 + 0)*16 + quad*4;
      int ch1 = (wave*2 + 1)*16 + quad*4;
      u16x4 o0, o1;
      #pragma unroll
      for (int r = 0; r < 4; ++r){ o0[r] = f2b(acc0[r]); o1[r] = f2b(acc1[r]); }
      *(u16x4*)(hh + (size_t)node*HID + ch0) = o0;
      *(u16x4*)(hh + (size_t)node*HID + ch1) = o1;
    }

    if (t + G >= NROWT) break;
    t += G; p ^= 1;
    ha = hb; ga = gb;     // rotate register sets
    hb = hc; gb = gc;
  }
}

// ---------------- attention core (Tier B single-node form, 64 lanes x 4 ch) ----------------
// Softmax without max-subtraction (shift-invariant; scores O(few), pre-scaled by log2e).
// Scalar rolling pipeline: index 2-ahead, row/score 1-ahead.
template<int H>
__device__ __forceinline__ void attn_node(int n, int lane, int beg, int end,
    const u16* __restrict__ hh, const float* __restrict__ ssrc,
    const float* __restrict__ sdst, const int* __restrict__ ssorted, float r[4]){
  const u32 f0 = (u32)lane*4u;
  const int hl = (H == 8) ? (lane >> 3) : 0;
  if (beg < 0) beg = 0;
  if (end > E_TOT) end = E_TOT;
  r[0] = r[1] = r[2] = r[3] = 0.f;
  if (beg >= end) return;
  float sd = sdst[(u32)n*H + hl];
  const int last = end - 1;

  // prologue: current edge (beg) fully issued; next index fetched
  int s0 = ssorted[beg];
  s0 = ((unsigned)s0 < N_NODESC) ? s0 : n;
  u16x4 v0 = *(const u16x4*)(hh + (u32)s0*HID + f0);
  float e0 = ssrc[(u32)s0*H + hl];
  int s1 = ssorted[min(beg+1, last)];

  float lval = 0.f, o0 = 0.f, o1 = 0.f, o2 = 0.f, o3 = 0.f;
  for (int i = beg; i < end; ++i){
    int s2 = ssorted[min(i+2, last)];                     // index 2-ahead
    int g1 = ((unsigned)s1 < N_NODESC) ? s1 : n;          // guard 1-ahead
    u16x4 v1 = *(const u16x4*)(hh + (u32)g1*HID + f0);    // row 1-ahead
    float e1 = ssrc[(u32)g1*H + hl];
    // compute current edge
    float ev = e0 + sd;
    ev = fmaxf(fmaxf(ev, NEG_SLOPE*ev), -87.f);   // leaky-relu + underflow guard (v_max3)
    ev = fminf(ev, 87.f);                          // overflow/NaN guard
    float wv = fexp2(ev);
    lval += wv;
    o0 += wv*b2f(v0[0]);
    o1 += wv*b2f(v0[1]);
    o2 += wv*b2f(v0[2]);
    o3 += wv*b2f(v0[3]);
    v0 = v1; e0 = e1; s1 = s2;
  }
  float inv = (lval > 0.f) ? 1.f/lval : 0.f;
  r[0] = o0*inv; r[1] = o1*inv; r[2] = o2*inv; r[3] = o3*inv;
}

// ---------------- Tier A paired attention: wave = 2 consecutive nodes ----------------
// Lanes 0-31 own node 2p (8 ch each, u16x8 rows), lanes 32-63 own node 2p+1.
// Per-iteration scalar chain (index/guard/score/exp) serves TWO edges; two independent
// gather chains per wave double memory-level parallelism. Loop runs max(degA,degB),
// tail-masked per half. begB == endA so one 3-int soff read covers the pair.
template<int H>
__device__ __forceinline__ void attn_gout_loop2(const u16* __restrict__ hh,
    const float* __restrict__ ssrc, const float* __restrict__ sdst,
    const int* __restrict__ soff, const int* __restrict__ ssorted,
    u16* __restrict__ gout, float s[8], float q[8]){
  int tid = threadIdx.x;
  int wid = tid >> 6, lane = tid & 63;
  int half = lane >> 5, l5 = lane & 31;
  const u32 c0 = (u32)l5*8u;
  const int hl = (H == 8) ? (l5 >> 2) : 0;
  int pw = blockIdx.x*4 + wid;
  const int npw = gridDim.x*4;
  // prologue: soff triple for first pair
  int sA = 0, sM = 0, sE = 0;
  if (pw < NPAIR){
    int n0 = pw*2;
    sA = soff[n0]; sM = soff[n0+1]; sE = soff[n0+2];
  }
  for (; pw < NPAIR; pw += npw){
    int n = pw*2 + half;
    // lookahead: next pair's soff triple
    int pw2 = pw + npw;
    int tA = 0, tM = 0, tE = 0;
    if (pw2 < NPAIR){
      int m0 = pw2*2;
      tA = soff[m0]; tM = soff[m0+1]; tE = soff[m0+2];
    }
    int beg   = half ? sM : sA;
    int myDeg = half ? (sE - sM) : (sM - sA);
    int dmax  = max(sM - sA, sE - sM);
    if (myDeg < 0) myDeg = 0;
    int dM1 = (myDeg > 0) ? (myDeg - 1) : 0;
    float sd = sdst[(u32)n*H + hl];

    float lval = 0.f;
    float o0=0.f,o1=0.f,o2=0.f,o3=0.f,o4=0.f,o5=0.f,o6=0.f,o7=0.f;
    if (dmax > 0){
      // prologue: edge 0 fully issued, edge 1 index fetched
      int ad0 = min(beg, E_TOT-1);
      int s0 = ssorted[ad0];
      s0 = ((unsigned)s0 < N_NODESC) ? s0 : n;
      u16x8 v0 = *(const u16x8*)(hh + (u32)s0*HID + c0);
      float e0 = ssrc[(u32)s0*H + hl];
      int s1 = ssorted[min(beg + min(1, dM1), E_TOT-1)];
      for (int d = 0; d < dmax; ++d){
        int s2 = ssorted[min(beg + min(d+2, dM1), E_TOT-1)];   // index 2-ahead
        int g1 = ((unsigned)s1 < N_NODESC) ? s1 : n;            // guard 1-ahead
        u16x8 v1 = *(const u16x8*)(hh + (u32)g1*HID + c0);      // row 1-ahead
        float e1 = ssrc[(u32)g1*H + hl];
        float ev = e0 + sd;
        ev = fmaxf(fmaxf(ev, NEG_SLOPE*ev), -87.f);   // leaky-relu + underflow guard
        ev = fminf(ev, 87.f);                          // overflow/NaN guard
        float wv = fexp2(ev);
        wv = (d < myDeg) ? wv : 0.f;                   // per-half tail mask
        lval += wv;
        o0 += wv*b2f(v0[0]); o1 += wv*b2f(v0[1]);
        o2 += wv*b2f(v0[2]); o3 += wv*b2f(v0[3]);
        o4 += wv*b2f(v0[4]); o5 += wv*b2f(v0[5]);
        o6 += wv*b2f(v0[6]); o7 += wv*b2f(v0[7]);
        v0 = v1; e0 = e1; s1 = s2;
      }
    }
    float inv = (lval > 0.f) ? 1.f/lval : 0.f;
    float r0=o0*inv, r1=o1*inv, r2=o2*inv, r3=o3*inv;
    float r4=o4*inv, r5=o5*inv, r6=o6*inv, r7=o7*inv;
    u16x8 og;
    og[0]=f2b(r0); og[1]=f2b(r1); og[2]=f2b(r2); og[3]=f2b(r3);
    og[4]=f2b(r4); og[5]=f2b(r5); og[6]=f2b(r6); og[7]=f2b(r7);
    *(u16x8*)(gout + (u32)n*HID + c0) = og;
    s[0]+=r0; s[1]+=r1; s[2]+=r2; s[3]+=r3;
    s[4]+=r4; s[5]+=r5; s[6]+=r6; s[7]+=r7;
    q[0]+=r0*r0; q[1]+=r1*r1; q[2]+=r2*r2; q[3]+=r3*r3;
    q[4]+=r4*r4; q[5]+=r5*r5; q[6]+=r6*r6; q[7]+=r7*r7;
    sA = tA; sM = tM; sE = tE;
  }
}

__global__ __launch_bounds__(256) void k_attn_gout(const u16* __restrict__ hh,
    const float* __restrict__ ssrc, const float* __restrict__ sdst,
    const int* __restrict__ soff, const int* __restrict__ ssorted,
    u16* __restrict__ gout, int H, float* __restrict__ bnpart){
  __shared__ float lsum[4*512];   // [wave][lane*8+j]; lane<32 -> ch c, lane>=32 -> 256+ch
  __shared__ float lsq [4*512];
  int tid = threadIdx.x, wid = tid >> 6, lane = tid & 63;
  float s[8] = {0.f,0.f,0.f,0.f,0.f,0.f,0.f,0.f};
  float q[8] = {0.f,0.f,0.f,0.f,0.f,0.f,0.f,0.f};
  if (H == 8) attn_gout_loop2<8>(hh, ssrc, sdst, soff, ssorted, gout, s, q);
  else        attn_gout_loop2<1>(hh, ssrc, sdst, soff, ssorted, gout, s, q);
  #pragma unroll
  for (int j = 0; j < 8; ++j){
    lsum[wid*512 + lane*8 + j] = s[j];
    lsq [wid*512 + lane*8 + j] = q[j];
  }
  __syncthreads();
  int c = tid;
  float ts = 0.f, tq = 0.f;
  #pragma unroll
  for (int w = 0; w < 4; ++w){
    ts += lsum[w*512 + c] + lsum[w*512 + 256 + c];
    tq += lsq [w*512 + c] + lsq [w*512 + 256 + c];
  }
  float* prow = bnpart + (size_t)(blockIdx.x & (NPART-1))*512;
  atomicAdd(&prow[c], ts);
  atomicAdd(&prow[HID + c], tq);
}

// Tier B pass 1: recompute attention, block-reduce BN stats into partials
template<int H>
__device__ __forceinline__ void attn_stats_loop(const u16* __restrict__ hh,
    const float* __restrict__ ssrc, const float* __restrict__ sdst,
    const int* __restrict__ soff, const int* __restrict__ ssorted,
    float s[4], float q[4]){
  int wid = threadIdx.x >> 6, lane = threadIdx.x & 63;
  int gw = blockIdx.x*4 + wid;
  int nw = gridDim.x*4;
  int beg = 0, end = 0;
  if (gw < N_NODESC){ beg = soff[gw]; end = soff[gw+1]; }
  for (int n = gw; n < N_NODESC; n += nw){
    int n2 = n + nw;
    int pb = 0, pe = 0;
    if (n2 < N_NODESC){ pb = soff[n2]; pe = soff[n2+1]; }
    float r[4];
    attn_node<H>(n, lane, beg, end, hh, ssrc, sdst, ssorted, r);
    #pragma unroll
    for (int j = 0; j < 4; ++j){ s[j] += r[j]; q[j] += r[j]*r[j]; }
    beg = pb; end = pe;
  }
}

__global__ __launch_bounds__(256) void k_attn_stats(const u16* __restrict__ hh,
    const float* __restrict__ ssrc, const float* __restrict__ sdst,
    const int* __restrict__ soff, const int* __restrict__ ssorted,
    float* __restrict__ bnpart, int H){
  __shared__ float lsum[4*HID];
  __shared__ float lsq[4*HID];
  int wid = threadIdx.x >> 6, lane = threadIdx.x & 63;
  float s[4] = {0.f,0.f,0.f,0.f}, q[4] = {0.f,0.f,0.f,0.f};
  if (H == 8) attn_stats_loop<8>(hh, ssrc, sdst, soff, ssorted, s, q);
  else        attn_stats_loop<1>(hh, ssrc, sdst, soff, ssorted, s, q);
  int f0 = lane*4;
  #pragma unroll
  for (int j = 0; j < 4; ++j){ lsum[wid*HID + f0 + j] = s[j]; lsq[wid*HID + f0 + j] = q[j]; }
  __syncthreads();
  int c = threadIdx.x;
  float ts = lsum[c] + lsum[HID+c] + lsum[2*HID+c] + lsum[3*HID+c];
  float tq = lsq[c]  + lsq[HID+c]  + lsq[2*HID+c]  + lsq[3*HID+c];
  float* prow = bnpart + (size_t)(blockIdx.x & (NPART-1))*512;
  atomicAdd(&prow[c], ts);
  atomicAdd(&prow[HID + c], tq);
}

// Tier B pass 2: recompute attention, fused BN+ReLU+residual into h
__global__ __launch_bounds__(256) void k_attn_apply(const u16* __restrict__ hh,
    const float* __restrict__ ssrc, const float* __restrict__ sdst,
    const int* __restrict__ soff, const int* __restrict__ ssorted,
    const float* __restrict__ scale, const float* __restrict__ shift,
    u16* __restrict__ h, int H){
  int wid = threadIdx.x >> 6, lane = threadIdx.x & 63;
  int n = blockIdx.x*4 + wid;
  if (n >= N_NODESC) return;
  int beg = soff[n], end = soff[n+1];
  float r[4];
  if (H == 8) attn_node<8>(n, lane, beg, end, hh, ssrc, sdst, ssorted, r);
  else        attn_node<1>(n, lane, beg, end, hh, ssrc, sdst, ssorted, r);
  int f0 = lane*4;
  const f32x4 sc = *(const f32x4*)(scale + f0);
  const f32x4 sh = *(const f32x4*)(shift + f0);
  u16x4 hv = *(u16x4*)(h + (size_t)n*HID + f0);
  u16x4 o;
  #pragma unroll
  for (int j = 0; j < 4; ++j){
    float t = r[j]*sc[j] + sh[j];
    t = (t > 0.f) ? t : 0.f;
    o[j] = f2b(b2f(hv[j]) + t);
  }
  *(u16x4*)(h + (size_t)n*HID + f0) = o;
}

// ---------------- BN finalize: reduce 64 partial rows -> scale/shift ----------------
__global__ __launch_bounds__(256) void k_bn_final(const float* __restrict__ bnpart,
    const void* __restrict__ gamma, const void* __restrict__ beta,
    float* __restrict__ scale, float* __restrict__ shift,
    const int* __restrict__ flagp, int loff){
  int f = *flagp;
  int c = threadIdx.x;
  float s = 0.f, q = 0.f;
  #pragma unroll 4
  for (int p = 0; p < NPART; ++p){
    s += bnpart[(size_t)p*512 + c];
    q += bnpart[(size_t)p*512 + HID + c];
  }
  float mu  = s * (1.f/N_NODESC);
  float var = q * (1.f/N_NODESC) - mu*mu;
  if (!(var >= 0.f)) var = 0.f;   // also catches NaN
  float sc = ldp(gamma, (size_t)loff + c, f) * rsqrtf(var + BN_EPSC);
  scale[c] = sc;
  shift[c] = ldp(beta, (size_t)loff + c, f) - mu*sc;
}

// ---------------- mean pool per graph (Tier B; batch sorted, counts fused) ----------------
__global__ __launch_bounds__(256) void k_pool(const u16* __restrict__ h,
    const int* __restrict__ batch, float* __restrict__ gsum, int* __restrict__ gcnt){
  int c = threadIdx.x;
  int r0 = blockIdx.x * 256;
  int r1 = min(r0 + 256, N_NODESC);
  if (r0 >= N_NODESC) return;
  int cur = batch[r0];
  float acc = 0.f;
  int nacc = 0;
  for (int r = r0; r < r1; ++r){
    int b = batch[r];
    if ((unsigned)b >= NGRAPHS) continue;
    if (b != cur){
      if ((unsigned)cur < NGRAPHS){
        atomicAdd(&gsum[cur*HID + c], acc);
        if (c == 0) atomicAdd(&gcnt[cur], nacc);
      }
      acc = 0.f; nacc = 0; cur = b;
    }
    acc += b2f(h[(size_t)r*HID + c]);
    nacc++;
  }
  if ((unsigned)cur < NGRAPHS){
    atomicAdd(&gsum[cur*HID + c], acc);
    if (c == 0) atomicAdd(&gcnt[cur], nacc);
  }
}

// Tier A: pool fused with last layer's BN+ReLU+residual.
__global__ __launch_bounds__(256) void k_pool_fused(const u16* __restrict__ h,
    const u16* __restrict__ gout, const float* __restrict__ scale, const float* __restrict__ shift,
    const int* __restrict__ batch, float* __restrict__ gsum, int* __restrict__ gcnt){
  __shared__ int lb[64];
  int tid = threadIdx.x;
  int r0 = blockIdx.x*64;
  if (tid < 64){
    int rr = r0 + tid;
    lb[tid] = (rr < N_NODESC) ? batch[rr] : -1;
  }
  __syncthreads();
  int wid = tid >> 6, lane = tid & 63;
  int c4 = lane*4;
  const f32x4 sc = *(const f32x4*)(scale + c4);
  const f32x4 sh = *(const f32x4*)(shift + c4);
  int rbase = r0 + wid*16;
  f32x4 acc = (f32x4){0.f,0.f,0.f,0.f};
  int nacc = 0, cur = -1;
  #pragma unroll 4
  for (int k = 0; k < 16; ++k){
    int r = rbase + k;
    if (r >= N_NODESC) break;
    int b = lb[wid*16 + k];
    if ((unsigned)b >= NGRAPHS) continue;
    if (b != cur){
      if ((unsigned)cur < NGRAPHS){
        atomicAdd(&gsum[cur*HID + c4+0], acc[0]);
        atomicAdd(&gsum[cur*HID + c4+1], acc[1]);
        atomicAdd(&gsum[cur*HID + c4+2], acc[2]);
        atomicAdd(&gsum[cur*HID + c4+3], acc[3]);
        if (lane == 0) atomicAdd(&gcnt[cur], nacc);
      }
      acc = (f32x4){0.f,0.f,0.f,0.f}; nacc = 0; cur = b;
    }
    const u16x4 hv = *(const u16x4*)(h    + (size_t)r*HID + c4);
    const u16x4 gv = *(const u16x4*)(gout + (size_t)r*HID + c4);
    #pragma unroll
    for (int j = 0; j < 4; ++j){
      float t = b2f(gv[j])*sc[j] + sh[j];
      t = (t > 0.f) ? t : 0.f;
      acc[j] += b2f(hv[j]) + t;
    }
    nacc++;
  }
  if ((unsigned)cur < NGRAPHS){
    atomicAdd(&gsum[cur*HID + c4+0], acc[0]);
    atomicAdd(&gsum[cur*HID + c4+1], acc[1]);
    atomicAdd(&gsum[cur*HID + c4+2], acc[2]);
    atomicAdd(&gsum[cur*HID + c4+3], acc[3]);
    if (lane == 0) atomicAdd(&gcnt[cur], nacc);
  }
}

// ---------------- G prep: mean-divide and convert to bf16 (64 KB, L2-resident) ----------------
__global__ __launch_bounds__(256) void k_gprep(const float* __restrict__ gsum,
    const int* __restrict__ gcnt, u16* __restrict__ gbf){
  int g = blockIdx.x, c = threadIdx.x;
  int cc = gcnt[g]; if (cc < 1) cc = 1;
  gbf[g*HID + c] = f2b(gsum[(size_t)g*HID + c] * (1.f/(float)cc));
}

// ---------------- token predictors: MFMA GEMM  preds[s] = G[128,256] @ W_s[256,5002] ----------------
__global__ __launch_bounds__(256) void k_pred(const u16* __restrict__ gbf,
    const void* __restrict__ tokW, const void* __restrict__ tokb, void* __restrict__ out,
    const int* __restrict__ flagp){
  int f = *flagp;
  int wave = threadIdx.x >> 6, lane = threadIdx.x & 63;
  int m = lane & 15, quad = lane >> 4;
  int s = blockIdx.y;
  int v = blockIdx.x*64 + wave*16 + m;       // this lane's vocab column
  bool vok = (v < VOCABC);

  f32x4 acc[8];
  #pragma unroll
  for (int t = 0; t < 8; ++t) acc[t] = (f32x4){0.f,0.f,0.f,0.f};

  const size_t wrow = (size_t)s*HID*VOCABC + v;
  #pragma unroll
  for (int ks = 0; ks < 8; ++ks){
    int kb = ks*32 + quad*8;
    short8 b;
    #pragma unroll
    for (int j = 0; j < 8; ++j)
      b[j] = vok ? (short)f2b(ldp(tokW, wrow + (size_t)(kb + j)*VOCABC, f)) : (short)0;
    #pragma unroll
    for (int t = 0; t < 8; ++t){
      const short8 a = *(const short8*)(gbf + (size_t)(t*16 + m)*HID + kb);
      acc[t] = __builtin_amdgcn_mfma_f32_16x16x32_bf16(a, b, acc[t], 0, 0, 0);
    }
  }

  float bb = vok ? ldp(tokb, (size_t)s*VOCABC + v, f) : 0.f;
  if (!vok) return;
  #pragma unroll
  for (int t = 0; t < 8; ++t){
    #pragma unroll
    for (int r = 0; r < 4; ++r){
      int grow = t*16 + quad*4 + r;
      float val = acc[t][r] + bb;
      size_t oi = ((size_t)(s*NGRAPHS + grow)*VOCABC) + v;
      if (f) ((float*)out)[oi] = val;
      else   ((u16*)out)[oi]   = f2b(val);
    }
  }
}

// ---------------- host launcher ----------------
extern "C" void kernel_launch(void* const* d_in, const int* in_sizes, int n_in,
                              void* d_out, int out_size, void* d_ws, size_t ws_size,
                              hipStream_t stream) {
  const int* x          = (const int*)d_in[0];
  const int* node_depth = (const int*)d_in[1];
  const int* edge_index = (const int*)d_in[2];
  const int* batch      = (const int*)d_in[3];
  const void* type_emb  = d_in[4];
  const void* attr_emb  = d_in[5];
  const void* depth_emb = d_in[6];
  const void* Ws        = d_in[7];
  const void* att_src   = d_in[8];
  const void* att_dst   = d_in[9];
  // d_in[10] = gat_bias: dropped (constant per channel cancels inside BatchNorm)
  const void* bn_gamma  = d_in[11];
  const void* bn_beta   = d_in[12];
  const void* tok_W     = d_in[13];
  const void* tok_b     = d_in[14];

  // ---- workspace carve ----
  char* base = (char*)d_ws;
  size_t off = 0;
  auto carve = [&](size_t bytes) -> void* {
    void* p = base + off;
    off += (bytes + 255) & ~(size_t)255;
    return p;
  };
  u16*   h     = (u16*)carve((size_t)N_NODESC*HID*2);     // 51.2 MB
  u16*   hh    = (u16*)carve((size_t)N_NODESC*HID*2);     // 51.2 MB
  float* ssrc  = (float*)carve((size_t)N_NODESC*8*4);     // 3.2 MB
  float* sdst  = (float*)carve((size_t)N_NODESC*8*4);     // 3.2 MB
  int*   soff  = (int*)carve((size_t)(N_NODESC+1)*4);
  int*   cursor= (int*)carve((size_t)N_NODESC*4);
  int*   ssorted=(int*)carve((size_t)E_TOT*4);            // 2.0 MB
  int*   btot  = (int*)carve((size_t)NCHUNK*4);
  int*   boff  = (int*)carve((size_t)NCHUNK*4);
  u16*   WT    = (u16*)carve((size_t)NLAYERS*HID*HID*2);  // 0.5 MB
  u16*   VAT   = (u16*)carve((size_t)NLAYERS*16*HID*2);   // 32 KB fused-score matrices
  float* bnpart= (float*)carve((size_t)NPART*512*4);      // 128 KB BN partials
  float* bnscale=(float*)carve(HID*4);
  float* bnshift=(float*)carve(HID*4);
  float* gsum  = (float*)carve((size_t)NGRAPHS*HID*4);    // 128 KB
  int*   gcnt  = (int*)carve((size_t)NGRAPHS*4);          // adjacent to gsum
  u16*   gbf   = (u16*)carve((size_t)NGRAPHS*HID*2);      // 64 KB bf16 pooled graphs
  int*   dflag = (int*)carve(256);
  size_t common = off;
  u16*   gout  = (u16*)carve((size_t)N_NODESC*HID*2);     // +51.2 MB
  const bool useGout = (off <= ws_size);
  if (common > ws_size) return;  // cannot run at all

  const int EB  = (E_TOT + 255)/256;
  const int NB4 = (N_NODESC + 3)/4;      // wave-per-node kernels

  // dtype detection first
  k_detect<<<1, 64, 0, stream>>>(type_emb, dflag);

  // setup (k_embed also zeroes cursor; k_prep = transW + prepVA fused)
  k_embed<<<NCH64, 256, 0, stream>>>(x, node_depth, type_emb, attr_emb, depth_emb, h, dflag, cursor);
  k_prep<<<256*NLAYERS + NLAYERS, 256, 0, stream>>>(Ws, WT, att_src, att_dst, VAT, dflag);
  k_hist<<<EB, 256, 0, stream>>>(edge_index, cursor);
  k_scan_part<<<NCHUNK, 256, 0, stream>>>(cursor, soff, btot);
  k_scan_tot<<<1, 256, 0, stream>>>(btot, boff, soff + N_NODESC);
  k_scan_add<<<NCHUNK, 256, 0, stream>>>(soff, boff, cursor);   // also zeroes cursor
  k_scatter<<<EB, 256, 0, stream>>>(edge_index, soff, cursor, ssorted);

  // layers — Tier A: bn_apply of layer l-1 and scores fused into gemm of layer l
  for (int l = 0; l < NLAYERS; ++l){
    int H = (l == NLAYERS-1) ? 1 : 8;
    int doApply = (useGout && l > 0) ? 1 : 0;
    k_gemm<<<GEMMB, 512, 0, stream>>>(h, gout, bnscale, bnshift, doApply,
                                     WT + (size_t)l*HID*HID, VAT + (size_t)l*16*HID,
                                     hh, ssrc, sdst, H, bnpart);
    if (useGout){
      k_attn_gout<<<ATTNB, 256, 0, stream>>>(hh, ssrc, sdst, soff, ssorted, gout, H, bnpart);
      k_bn_final<<<1, 256, 0, stream>>>(bnpart, bn_gamma, bn_beta, bnscale, bnshift, dflag, l*HID);
    } else {
      k_attn_stats<<<2048, 256, 0, stream>>>(hh, ssrc, sdst, soff, ssorted, bnpart, H);
      k_bn_final<<<1, 256, 0, stream>>>(bnpart, bn_gamma, bn_beta, bnscale, bnshift, dflag, l*HID);
      k_attn_apply<<<NB4, 256, 0, stream>>>(hh, ssrc, sdst, soff, ssorted, bnscale, bnshift, h, H);
    }
  }

  // pool (gsum+gcnt adjacent -> single zero launch)
  k_zero<<<(NGRAPHS*HID + NGRAPHS + 255)/256, 256, 0, stream>>>((int*)gsum, NGRAPHS*HID + NGRAPHS);
  if (useGout)
    k_pool_fused<<<NCH64, 256, 0, stream>>>(h, gout, bnscale, bnshift, batch, gsum, gcnt);
  else
    k_pool<<<NCHUNK, 256, 0, stream>>>(h, batch, gsum, gcnt);
  k_gprep<<<NGRAPHS, 256, 0, stream>>>(gsum, gcnt, gbf);

  // predictors (MFMA GEMM)
  k_pred<<<dim3(NVQ, SEQLEN), 256, 0, stream>>>(gbf, tok_W, tok_b, d_out, dflag);
}